// Round 1
// baseline (184.531 us; speedup 1.0000x reference)
//
#include <hip/hip_runtime.h>

// ContinuousVariableQNN: out[b,i] = 0.25*(dsum[i] + mux^2 + mup^2) - 0.5
// where mu = (2*inputs) @ (S[:,0::2])^T, S = prod_l (C @ D_l), dsum = row-pair norms of S.
// C has closed form (pi/4 beamsplitter chain => geometric lower-triangular per x/p subspace).
// All matmuls via mfma_f32_16x16x32_bf16 with hi/lo split (3-pass) for ~fp32 precision.

#define BATCH 131072

typedef __attribute__((ext_vector_type(8))) short bf16x8;
typedef __attribute__((ext_vector_type(4))) float f32x4;

#define MFMA(a, b, c) __builtin_amdgcn_mfma_f32_16x16x32_bf16(a, b, c, 0, 0, 0)

__device__ __forceinline__ unsigned short f2bf(float f) {
  unsigned int u = __float_as_uint(f);
  u += 0x7FFFu + ((u >> 16) & 1u);
  return (unsigned short)(u >> 16);
}
__device__ __forceinline__ float bf2f(unsigned short h) {
  return __uint_as_float(((unsigned int)h) << 16);
}
__device__ __forceinline__ void pack8(const float* v, uint4& hv, uint4& lv) {
  unsigned int hw[4], lw[4];
#pragma unroll
  for (int p = 0; p < 4; ++p) {
    unsigned short h0 = f2bf(v[2 * p]), h1 = f2bf(v[2 * p + 1]);
    unsigned short l0 = f2bf(v[2 * p] - bf2f(h0)), l1 = f2bf(v[2 * p + 1] - bf2f(h1));
    hw[p] = (unsigned int)h0 | ((unsigned int)h1 << 16);
    lw[p] = (unsigned int)l0 | ((unsigned int)l1 << 16);
  }
  hv = make_uint4(hw[0], hw[1], hw[2], hw[3]);
  lv = make_uint4(lw[0], lw[1], lw[2], lw[3]);
}

// ---------------- K1: build M_l = C @ D_l from closed form --------------------
// odd l -> row-major [i][j]; even l -> col-major [j][i] (so products never transpose)
__global__ __launch_bounds__(256) void build_m(const float* __restrict__ params,
                                               unsigned short* __restrict__ Mhi,
                                               unsigned short* __restrict__ Mlo) {
  int bx = blockIdx.x;  // 0..2047
  int l = bx >> 8;
  int idx = bx & 255;
  int t = threadIdx.x;
  int i, j;
  if (l & 1) { i = idx; j = t; } else { j = idx; i = t; }
  int a = i >> 1, nn = j >> 1;
  float cx;
  if (a < 127) {
    if (nn == 0) cx = exp2f(-0.5f * (float)(a + 1));
    else if (nn <= a) cx = exp2f(-0.5f * (float)(a - nn + 2));
    else if (nn == a + 1) cx = -0.70710678118654752f;
    else cx = 0.0f;
  } else {
    cx = (nn == 0) ? exp2f(-63.5f) : exp2f(-0.5f * (float)(128 - nn));
  }
  const float* p = params + l * 384 + nn * 3;
  float th1 = p[0], r = p[1], th2 = p[2];
  float c1 = cosf(th1), s1 = sinf(th1);
  float c2 = cosf(th2), s2 = sinf(th2);
  float em = expf(-r), ep = expf(r);
  float bb;
  if (i & 1) bb = (j & 1) ? (-s2 * s1 * em + c2 * c1 * ep) : (s2 * c1 * em + c2 * s1 * ep);
  else       bb = (j & 1) ? (-c2 * s1 * em - s2 * c1 * ep) : (c2 * c1 * em - s2 * s1 * ep);
  float v = cx * bb;
  unsigned short hi = f2bf(v);
  unsigned short lo = f2bf(v - bf2f(hi));
  int off = l * 65536 + ((l & 1) ? (i * 256 + j) : (j * 256 + i));
  Mhi[off] = hi;
  Mlo[off] = lo;
}

// ---------------- K2: Out_pair = In[2p+1] @ In[2p], 256x256x256, split-bf16 ---
#define PSTR 40  // 32 k + 8 pad (shorts); row stride 80 B -> 2-way-max bank aliasing
__global__ __launch_bounds__(256) void matprod(
    const unsigned short* __restrict__ Lhi_base, const unsigned short* __restrict__ Llo_base,
    const unsigned short* __restrict__ Rhi_base, const unsigned short* __restrict__ Rlo_base,
    unsigned short* __restrict__ Ohi, unsigned short* __restrict__ Olo,
    float* __restrict__ Sout, int final_mode) {
  __shared__ __align__(16) char lds_raw[4 * 128 * PSTR * 2];  // 40960 B
  unsigned short* sLhi = (unsigned short*)lds_raw;
  unsigned short* sLlo = sLhi + 128 * PSTR;
  unsigned short* sRhi = sLlo + 128 * PSTR;
  unsigned short* sRlo = sRhi + 128 * PSTR;
  float* sEp = (float*)lds_raw;  // epilogue reuse: [64][129] f32 = 33024 B

  int bx = blockIdx.x;
  int pair = bx >> 2, tile = bx & 3;
  int tr = tile >> 1, tc = tile & 1;
  const unsigned short* Lhi = Lhi_base + (2 * pair + 1) * 65536;  // row-major
  const unsigned short* Llo = Llo_base + (2 * pair + 1) * 65536;
  const unsigned short* Rhi = Rhi_base + (2 * pair) * 65536;      // col-major [n][k]
  const unsigned short* Rlo = Rlo_base + (2 * pair) * 65536;

  int t = threadIdx.x;
  int lane = t & 63, w = t >> 6;
  int wr = (w >> 1) * 64, wc = (w & 1) * 64;
  int l15 = lane & 15, q = lane >> 4;

  f32x4 acc[4][4];
#pragma unroll
  for (int a = 0; a < 4; ++a)
#pragma unroll
    for (int b = 0; b < 4; ++b) acc[a][b] = (f32x4){0.f, 0.f, 0.f, 0.f};

  for (int kc = 0; kc < 256; kc += 32) {
    __syncthreads();
#pragma unroll
    for (int it = 0; it < 2; ++it) {
      int e = it * 2048 + t * 8;
      int row = e >> 5, k = e & 31;
      *(uint4*)(sLhi + row * PSTR + k) = *(const uint4*)(Lhi + (tr * 128 + row) * 256 + kc + k);
      *(uint4*)(sLlo + row * PSTR + k) = *(const uint4*)(Llo + (tr * 128 + row) * 256 + kc + k);
      *(uint4*)(sRhi + row * PSTR + k) = *(const uint4*)(Rhi + (tc * 128 + row) * 256 + kc + k);
      *(uint4*)(sRlo + row * PSTR + k) = *(const uint4*)(Rlo + (tc * 128 + row) * 256 + kc + k);
    }
    __syncthreads();
    int kb = q * 8;
    bf16x8 afh[4], afl[4], bfh[4], bfl[4];
#pragma unroll
    for (int rt = 0; rt < 4; ++rt) {
      int r = wr + rt * 16 + l15;
      afh[rt] = *(const bf16x8*)(sLhi + r * PSTR + kb);
      afl[rt] = *(const bf16x8*)(sLlo + r * PSTR + kb);
      int n = wc + rt * 16 + l15;
      bfh[rt] = *(const bf16x8*)(sRhi + n * PSTR + kb);
      bfl[rt] = *(const bf16x8*)(sRlo + n * PSTR + kb);
    }
#pragma unroll
    for (int rt = 0; rt < 4; ++rt)
#pragma unroll
      for (int ct = 0; ct < 4; ++ct) {
        acc[rt][ct] = MFMA(afh[rt], bfh[ct], acc[rt][ct]);
        acc[rt][ct] = MFMA(afh[rt], bfl[ct], acc[rt][ct]);
        acc[rt][ct] = MFMA(afl[rt], bfh[ct], acc[rt][ct]);
      }
  }

  // Epilogue via LDS (two 64-row phases to stay under LDS budget), coalesced stores
  for (int ph = 0; ph < 2; ++ph) {
    __syncthreads();
    if (wr == ph * 64) {
#pragma unroll
      for (int rt = 0; rt < 4; ++rt)
#pragma unroll
        for (int ct = 0; ct < 4; ++ct) {
          int rl = rt * 16 + q * 4;
          int col = wc + ct * 16 + l15;
#pragma unroll
          for (int rg = 0; rg < 4; ++rg) sEp[(rl + rg) * 129 + col] = acc[rt][ct][rg];
        }
    }
    __syncthreads();
    if (final_mode) {
      int rl = t >> 2, cseg = (t & 3) * 32;
      for (int cc = 0; cc < 32; cc += 4) {
        int c = cseg + cc;
        *(float4*)(Sout + (tr * 128 + ph * 64 + rl) * 256 + tc * 128 + c) =
            make_float4(sEp[rl * 129 + c], sEp[rl * 129 + c + 1],
                        sEp[rl * 129 + c + 2], sEp[rl * 129 + c + 3]);
      }
    } else if (pair & 1) {  // row-major output (used as L next level)
      int rl = t >> 2, cseg = (t & 3) * 32;
      for (int cc = 0; cc < 32; cc += 8) {
        float v[8];
#pragma unroll
        for (int jj = 0; jj < 8; ++jj) v[jj] = sEp[rl * 129 + cseg + cc + jj];
        uint4 hv, lv;
        pack8(v, hv, lv);
        int off = pair * 65536 + (tr * 128 + ph * 64 + rl) * 256 + tc * 128 + cseg + cc;
        *(uint4*)(Ohi + off) = hv;
        *(uint4*)(Olo + off) = lv;
      }
    } else {  // col-major output (used as R next level)
      int col = t >> 1, rseg = (t & 1) * 32;
      for (int cc = 0; cc < 32; cc += 8) {
        float v[8];
#pragma unroll
        for (int jj = 0; jj < 8; ++jj) v[jj] = sEp[(rseg + cc + jj) * 129 + col];
        uint4 hv, lv;
        pack8(v, hv, lv);
        int off = pair * 65536 + (tc * 128 + col) * 256 + tr * 128 + ph * 64 + rseg + cc;
        *(uint4*)(Ohi + off) = hv;
        *(uint4*)(Olo + off) = lv;
      }
    }
  }
}

// ---------------- K3: pack W into B-frag order + dsum -------------------------
// W'[n][k] = 2*S[sigma(n)][2k]; n<128 -> x row 2n, n>=128 -> p row 2(n-128)+1.
// Whi/Wlo layout: ((ct*4+ks)*64 + lane)*8 + j  => wave frag load = 1 contiguous KiB.
__global__ __launch_bounds__(64) void pack_w(const float* __restrict__ S,
                                             unsigned short* __restrict__ Whi,
                                             unsigned short* __restrict__ Wlo,
                                             float* __restrict__ dsum) {
  int b = blockIdx.x;
  int lane = threadIdx.x;
  if (b < 64) {
    int ct = b >> 2, ks = b & 3;
    int n = ct * 16 + (lane & 15);
    int k0 = ks * 32 + (lane >> 4) * 8;
    int srow = (n < 128) ? (2 * n) : (2 * (n - 128) + 1);
    float v[8];
#pragma unroll
    for (int jj = 0; jj < 8; ++jj) v[jj] = 2.0f * S[srow * 256 + 2 * (k0 + jj)];
    uint4 hv, lv;
    pack8(v, hv, lv);
    int off = ((ct * 4 + ks) * 64 + lane) * 8;
    *(uint4*)(Whi + off) = hv;
    *(uint4*)(Wlo + off) = lv;
  } else {
    int i = (b - 64) * 64 + lane;  // 0..127
    const float* r0 = S + (2 * i) * 256;
    const float* r1 = r0 + 256;
    float s = 0.f;
    for (int k = 0; k < 256; ++k) s += r0[k] * r0[k] + r1[k] * r1[k];
    dsum[i] = s;
  }
}

// ---------------- K4: main batched GEMM + fused epilogue ----------------------
// Block: 64 batch rows x full N=256, 4 waves (2x2): wave = 32 rows x 128 cols.
__global__ __launch_bounds__(256) void qnn_gemm(
    const float* __restrict__ A, const unsigned short* __restrict__ Whi,
    const unsigned short* __restrict__ Wlo, const float* __restrict__ dsum,
    float* __restrict__ out) {
  __shared__ unsigned short sAhi[64 * 136];  // +8 shorts row pad
  __shared__ unsigned short sAlo[64 * 136];
  int t = threadIdx.x;
  int lane = t & 63, w = t >> 6;
  int wr = w >> 1, wc = w & 1;
  int l15 = lane & 15, q = lane >> 4;
  long brow0 = (long)blockIdx.x * 64;

  // Stage A tile (fp32 -> hi/lo bf16), coalesced float4 loads
#pragma unroll
  for (int it = 0; it < 8; ++it) {
    int e = it * 1024 + t * 4;
    int row = e >> 7, k = e & 127;
    float4 v = *(const float4*)(A + (brow0 + row) * 128 + k);
    unsigned short h0 = f2bf(v.x), h1 = f2bf(v.y), h2 = f2bf(v.z), h3 = f2bf(v.w);
    unsigned short l0 = f2bf(v.x - bf2f(h0)), l1 = f2bf(v.y - bf2f(h1));
    unsigned short l2 = f2bf(v.z - bf2f(h2)), l3 = f2bf(v.w - bf2f(h3));
    *(uint2*)(sAhi + row * 136 + k) =
        make_uint2((unsigned)h0 | ((unsigned)h1 << 16), (unsigned)h2 | ((unsigned)h3 << 16));
    *(uint2*)(sAlo + row * 136 + k) =
        make_uint2((unsigned)l0 | ((unsigned)l1 << 16), (unsigned)l2 | ((unsigned)l3 << 16));
  }
  __syncthreads();

  f32x4 acc[2][4][2];
#pragma unroll
  for (int rt = 0; rt < 2; ++rt)
#pragma unroll
    for (int qq = 0; qq < 4; ++qq)
#pragma unroll
      for (int xp = 0; xp < 2; ++xp) acc[rt][qq][xp] = (f32x4){0.f, 0.f, 0.f, 0.f};

#pragma unroll
  for (int ks = 0; ks < 4; ++ks) {
    int kb = ks * 32 + q * 8;
    bf16x8 ah[2], al[2];
#pragma unroll
    for (int rt = 0; rt < 2; ++rt) {
      int row = wr * 32 + rt * 16 + l15;
      ah[rt] = *(const bf16x8*)(sAhi + row * 136 + kb);
      al[rt] = *(const bf16x8*)(sAlo + row * 136 + kb);
    }
#pragma unroll
    for (int qq = 0; qq < 4; ++qq)
#pragma unroll
      for (int xp = 0; xp < 2; ++xp) {
        int ct = wc * 4 + qq + 8 * xp;
        int off = ((ct * 4 + ks) * 64 + lane) * 8;
        bf16x8 bh = *(const bf16x8*)(Whi + off);
        bf16x8 bl = *(const bf16x8*)(Wlo + off);
#pragma unroll
        for (int rt = 0; rt < 2; ++rt) {
          acc[rt][qq][xp] = MFMA(ah[rt], bh, acc[rt][qq][xp]);
          acc[rt][qq][xp] = MFMA(ah[rt], bl, acc[rt][qq][xp]);
          acc[rt][qq][xp] = MFMA(al[rt], bh, acc[rt][qq][xp]);
        }
      }
  }

  // Fused epilogue: out = 0.25*(dsum + mux^2 + mup^2) - 0.5
#pragma unroll
  for (int qq = 0; qq < 4; ++qq) {
    int i = (wc * 4 + qq) * 16 + l15;
    float ds = dsum[i];
#pragma unroll
    for (int rt = 0; rt < 2; ++rt) {
      long row0 = brow0 + wr * 32 + rt * 16 + q * 4;
      f32x4 ax = acc[rt][qq][0];
      f32x4 ap = acc[rt][qq][1];
#pragma unroll
      for (int rg = 0; rg < 4; ++rg) {
        float val = 0.25f * (ds + ax[rg] * ax[rg] + ap[rg] * ap[rg]) - 0.5f;
        out[(row0 + rg) * 128 + i] = val;
      }
    }
  }
}

// ---------------- launcher ----------------------------------------------------
extern "C" void kernel_launch(void* const* d_in, const int* in_sizes, int n_in,
                              void* d_out, int out_size, void* d_ws, size_t ws_size,
                              hipStream_t stream) {
  const float* inputs = (const float*)d_in[0];   // [131072][128] f32
  const float* params = (const float*)d_in[1];   // [8][384] f32
  float* out = (float*)d_out;                    // [131072][128] f32

  unsigned short* Mhi = (unsigned short*)d_ws;           // 8 * 65536
  unsigned short* Mlo = Mhi + 8 * 65536;
  unsigned short* Phi = Mlo + 8 * 65536;                 // 4 * 65536
  unsigned short* Plo = Phi + 4 * 65536;
  unsigned short* Qhi = Plo + 4 * 65536;                 // 2 * 65536
  unsigned short* Qlo = Qhi + 2 * 65536;
  float* S = (float*)(Qlo + 2 * 65536);                  // 65536 f32
  unsigned short* Whi = (unsigned short*)(S + 65536);    // 65536
  unsigned short* Wlo = Whi + 65536;                     // 65536
  float* dsum = (float*)(Wlo + 65536);                   // 128 f32
  // total ws: ~4.1 MiB

  build_m<<<2048, 256, 0, stream>>>(params, Mhi, Mlo);
  matprod<<<16, 256, 0, stream>>>(Mhi, Mlo, Mhi, Mlo, Phi, Plo, nullptr, 0);  // P = M pairs
  matprod<<<8, 256, 0, stream>>>(Phi, Plo, Phi, Plo, Qhi, Qlo, nullptr, 0);   // Q = P pairs
  matprod<<<4, 256, 0, stream>>>(Qhi, Qlo, Qhi, Qlo, nullptr, nullptr, S, 1); // S = Q1@Q0
  pack_w<<<66, 64, 0, stream>>>(S, Whi, Wlo, dsum);
  qnn_gemm<<<2048, 256, 0, stream>>>(inputs, Whi, Wlo, dsum, out);
}